// Round 2
// baseline (4297.989 us; speedup 1.0000x reference)
//
#include <hip/hip_runtime.h>
#include <hip/hip_bf16.h>

typedef __hip_bfloat16 bf16;

// ---------------------------------------------------------------------------
// Threefry-2x32 (20 rounds), JAX partitionable mode:
//   bits(i) = x0 ^ x1 of threefry2x32(key=(0,42), counter=(hi=0, lo=i))
//   keep    = (bits >> 31) == 0   (uniform<0.5)
// ---------------------------------------------------------------------------
__device__ __forceinline__ bool keep_elem(unsigned idx) {
    const unsigned k0 = 0u, k1 = 42u;
    const unsigned k2 = k0 ^ k1 ^ 0x1BD11BDAu;
    unsigned x0 = k0;        // counts_hi (=0) + ks[0]
    unsigned x1 = idx + k1;  // counts_lo (=i) + ks[1]
#define TF_QR(R) { x0 += x1; x1 = (x1 << R) | (x1 >> (32 - R)); x1 ^= x0; }
    TF_QR(13) TF_QR(15) TF_QR(26) TF_QR(6)
    x0 += k1; x1 += k2 + 1u;
    TF_QR(17) TF_QR(29) TF_QR(16) TF_QR(24)
    x0 += k2; x1 += k0 + 2u;
    TF_QR(13) TF_QR(15) TF_QR(26) TF_QR(6)
    x0 += k0; x1 += k1 + 3u;
    TF_QR(17) TF_QR(29) TF_QR(16) TF_QR(24)
    x0 += k1; x1 += k2 + 4u;
    TF_QR(13) TF_QR(15) TF_QR(26) TF_QR(6)
    x0 += k2; x1 += k0 + 5u;
#undef TF_QR
    return (((x0 ^ x1) >> 31) & 1u) == 0u;
}

// ---------------------------------------------------------------------------
// Detection kernels.
// flag[0]: edges are int64 (1) vs int32 (0)
// flag[1]: x is f32 (1) vs bf16 (0);  flag[2]: weights f32 vs bf16
// ---------------------------------------------------------------------------
__global__ void detect_edges_k(const unsigned* __restrict__ w, int* __restrict__ flag) {
    __shared__ unsigned red[256];
    unsigned v = 0;
    for (int i = threadIdx.x; i < 2048; i += 256) v |= w[2 * i + 1];
    red[threadIdx.x] = v;
    __syncthreads();
    for (int s = 128; s > 0; s >>= 1) {
        if (threadIdx.x < s) red[threadIdx.x] |= red[threadIdx.x + s];
        __syncthreads();
    }
    if (threadIdx.x == 0) flag[0] = (red[0] == 0u) ? 1 : 0;
}

// If buffer is f32, the low 16 bits of each word are mantissa bits -> as bf16
// their exponent field is ~uniform (only ~16% "plausible"). Real bf16 data has
// ~100% plausible exponents on even-indexed elements. Zero tensors detect as
// bf16, which reads correct zeros under either true dtype.
__global__ void detect_f32_k(const unsigned short* __restrict__ w,
                             int* __restrict__ flag, int fidx) {
    __shared__ int red[256];
    int cnt = 0;
    for (int i = threadIdx.x; i < 1024; i += 256) {
        unsigned short b = w[2 * i];
        int e = (b >> 7) & 0xFF;
        if ((b & 0x7FFF) == 0 || (e >= 100 && e < 140)) cnt++;
    }
    red[threadIdx.x] = cnt;
    __syncthreads();
    for (int s = 128; s > 0; s >>= 1) {
        if (threadIdx.x < s) red[threadIdx.x] += red[threadIdx.x + s];
        __syncthreads();
    }
    if (threadIdx.x == 0) flag[fidx] = (red[0] < 614) ? 1 : 0;  // <60% plausible => f32
}

__global__ void convert_edges_k(const void* __restrict__ src, int* __restrict__ out,
                                int twoE, const int* __restrict__ flag) {
    int i = blockIdx.x * 256 + threadIdx.x;
    if (i >= twoE) return;
    if (flag[0]) out[i] = (int)((const unsigned long long*)src)[i];
    else         out[i] = ((const int*)src)[i];
}

__global__ void canon_k(const void* __restrict__ src, bf16* __restrict__ dst,
                        int n, const int* __restrict__ flag, int fidx) {
    int i = blockIdx.x * 256 + threadIdx.x;
    if (i >= n) return;
    if (flag[fidx]) dst[i] = __float2bfloat16(((const float*)src)[i]);
    else            dst[i] = ((const bf16*)src)[i];
}

// ---------------------------------------------------------------------------
// Degree / normalization
// ---------------------------------------------------------------------------
__global__ void deg_init_k(float* __restrict__ deg, int n) {
    int i = blockIdx.x * 256 + threadIdx.x;
    if (i < n) deg[i] = 1.0f;
}
__global__ void deg_accum_k(const int* __restrict__ edges, float* __restrict__ deg,
                            int E, int n) {
    int e = blockIdx.x * 256 + threadIdx.x;
    if (e >= E) return;
    int d = edges[E + e];
    d = (d < 0) ? 0 : (d >= n ? n - 1 : d);
    atomicAdd(&deg[d], 1.0f);
}
__global__ void deg_fin_k(float* __restrict__ deg, int n) {
    int i = blockIdx.x * 256 + threadIdx.x;
    if (i < n) deg[i] = rsqrtf(deg[i]);  // deg -> dinv in place
}

// ---------------------------------------------------------------------------
// Tiled GEMM: C[M,N] = A[M,K] @ B[K,N]; bf16 in, f32 accumulate, bf16 out.
// fuse_dropout: apply threefry keep mask (x2 scale) to A by flat index.
// ---------------------------------------------------------------------------
__global__ __launch_bounds__(256) void gemm_bf16_k(
    const bf16* __restrict__ A, const bf16* __restrict__ B, bf16* __restrict__ C,
    int M, int N, int K, int fuse_dropout) {
    __shared__ float As[32][64];  // [k][m]
    __shared__ float Bs[32][64];  // [k][n]
    const int t = threadIdx.x;
    const int m0 = blockIdx.x * 64;
    const int n0 = blockIdx.y * 64;
    const int tx = t & 15, ty = t >> 4;
    float acc[4][4] = {};

    for (int kk = 0; kk < K; kk += 32) {
        {   // A tile: 64 rows x 32 k, 8 consecutive-k elems per thread
            int q = t * 8;
            int r = q >> 5, c = q & 31;
            int row = m0 + r; if (row >= M) row = M - 1;
            const bf16* ap = A + (size_t)row * K + kk + c;
            unsigned base = (unsigned)row * (unsigned)K + (unsigned)(kk + c);
#pragma unroll
            for (int j = 0; j < 8; ++j) {
                float v = __bfloat162float(ap[j]);
                if (fuse_dropout) v = keep_elem(base + j) ? v * 2.0f : 0.0f;
                As[c + j][r] = v;
            }
        }
        {   // B tile: 32 k-rows x 64 n-cols
            int q = t * 8;
            int r = q >> 6, c = q & 63;
            const bf16* bp = B + (size_t)(kk + r) * N + n0 + c;
#pragma unroll
            for (int j = 0; j < 8; ++j) Bs[r][c + j] = __bfloat162float(bp[j]);
        }
        __syncthreads();
#pragma unroll
        for (int k = 0; k < 32; ++k) {
            float a[4], b[4];
#pragma unroll
            for (int i = 0; i < 4; ++i) a[i] = As[k][ty * 4 + i];
#pragma unroll
            for (int j = 0; j < 4; ++j) b[j] = Bs[k][tx * 4 + j];
#pragma unroll
            for (int i = 0; i < 4; ++i)
#pragma unroll
                for (int j = 0; j < 4; ++j) acc[i][j] += a[i] * b[j];
        }
        __syncthreads();
    }
#pragma unroll
    for (int i = 0; i < 4; ++i) {
        int row = m0 + ty * 4 + i;
        if (row < M) {
            bf16* cp = C + (size_t)row * N + n0 + tx * 4;
#pragma unroll
            for (int j = 0; j < 4; ++j) cp[j] = __float2bfloat16(acc[i][j]);
        }
    }
}

// ---------------------------------------------------------------------------
// Aggregation into an f32 buffer:
//   init:    out = t*self_norm + bias
//   scatter: out[dst] += t[src]*norm   (atomics)
// ---------------------------------------------------------------------------
__global__ void agg_init_k(const bf16* __restrict__ t, const bf16* __restrict__ bias,
                           const float* __restrict__ dinv, float* __restrict__ outp,
                           long long total, int logD) {
    long long i = (long long)blockIdx.x * 256 + threadIdx.x;
    if (i >= total) return;
    int row = (int)(i >> logD);
    int j = (int)(i & ((1 << logD) - 1));
    float dv = dinv[row];
    outp[i] = __bfloat162float(t[i]) * dv * dv + __bfloat162float(bias[j]);
}

__global__ void agg_scatter_k(const bf16* __restrict__ t, const int* __restrict__ edges,
                              const float* __restrict__ dinv, float* __restrict__ outp,
                              int E, int n, int logD) {
    long long i = (long long)blockIdx.x * 256 + threadIdx.x;
    long long total = ((long long)E) << logD;
    if (i >= total) return;
    int e = (int)(i >> logD);
    int j = (int)(i & ((1 << logD) - 1));
    int s = edges[e], d = edges[E + e];
    s = (s < 0) ? 0 : (s >= n ? n - 1 : s);
    d = (d < 0) ? 0 : (d >= n ? n - 1 : d);
    float v = __bfloat162float(t[((size_t)s << logD) + j]) * dinv[s] * dinv[d];
    atomicAdd(outp + (((size_t)d << logD) + j), v);
}

__global__ void relu_cvt_k(const float* __restrict__ in, bf16* __restrict__ out, long long n) {
    long long i = (long long)blockIdx.x * 256 + threadIdx.x;
    if (i < n) out[i] = __float2bfloat16(fmaxf(in[i], 0.0f));
}

// ---------------------------------------------------------------------------
extern "C" void kernel_launch(void* const* d_in, const int* in_sizes, int n_in,
                              void* d_out, int out_size, void* d_ws, size_t ws_size,
                              hipStream_t stream) {
    const void* xin  = d_in[0];
    const void* ei   = d_in[1];
    const void* W1in = d_in[2];
    const void* b1in = d_in[3];
    const void* Wmuin = d_in[4];
    const void* bmuin = d_in[5];
    const void* Wlsin = d_in[6];
    const void* blsin = d_in[7];
    float* out = (float*)d_out;  // reference output dtype: float32

    const int H    = in_sizes[3];        // 512
    const int DOUT = in_sizes[5];        // 256
    const int DIN  = in_sizes[2] / H;    // 512
    const int N    = in_sizes[0] / DIN;  // 50000
    const int E    = in_sizes[1] / 2;    // 800000
    const int logH = 9, logDOUT = 8;

    char* ws = (char*)d_ws;
    size_t off = 0;
    int* flag = (int*)(ws + off); off += 256;
    int* edges = (int*)(ws + off); off += (size_t)2 * E * 4; off = (off + 255) & ~(size_t)255;
    float* dinv = (float*)(ws + off); off += (size_t)N * 4; off = (off + 255) & ~(size_t)255;
    float* bufA = (float*)(ws + off); off += (size_t)N * H * 4; off = (off + 255) & ~(size_t)255;
    bf16* bufB = (bf16*)(ws + off); off += (size_t)N * H * 2; off = (off + 255) & ~(size_t)255;
    bf16* xcan = (bf16*)(ws + off); off += (size_t)N * DIN * 2; off = (off + 255) & ~(size_t)255;  // also h1
    bf16* W1c  = (bf16*)(ws + off); off += (size_t)DIN * H * 2; off = (off + 255) & ~(size_t)255;
    bf16* Wmuc = (bf16*)(ws + off); off += (size_t)H * DOUT * 2; off = (off + 255) & ~(size_t)255;
    bf16* Wlsc = (bf16*)(ws + off); off += (size_t)H * DOUT * 2; off = (off + 255) & ~(size_t)255;
    bf16* b1c  = (bf16*)(ws + off); off += (size_t)H * 2; off = (off + 255) & ~(size_t)255;
    bf16* bmuc = (bf16*)(ws + off); off += (size_t)DOUT * 2; off = (off + 255) & ~(size_t)255;
    bf16* blsc = (bf16*)(ws + off); off += (size_t)DOUT * 2; off = (off + 255) & ~(size_t)255;
    if (off > ws_size) return;

    const int twoE = 2 * E;
    hipLaunchKernelGGL(detect_edges_k, dim3(1), dim3(256), 0, stream, (const unsigned*)ei, flag);
    hipLaunchKernelGGL(detect_f32_k, dim3(1), dim3(256), 0, stream, (const unsigned short*)xin, flag, 1);
    hipLaunchKernelGGL(detect_f32_k, dim3(1), dim3(256), 0, stream, (const unsigned short*)W1in, flag, 2);

    hipLaunchKernelGGL(convert_edges_k, dim3((twoE + 255) / 256), dim3(256), 0, stream,
                       ei, edges, twoE, flag);
    int nx = N * DIN;
    hipLaunchKernelGGL(canon_k, dim3((nx + 255) / 256), dim3(256), 0, stream, xin, xcan, nx, flag, 1);
    hipLaunchKernelGGL(canon_k, dim3((DIN * H + 255) / 256), dim3(256), 0, stream, W1in, W1c, DIN * H, flag, 2);
    hipLaunchKernelGGL(canon_k, dim3((H * DOUT + 255) / 256), dim3(256), 0, stream, Wmuin, Wmuc, H * DOUT, flag, 2);
    hipLaunchKernelGGL(canon_k, dim3((H * DOUT + 255) / 256), dim3(256), 0, stream, Wlsin, Wlsc, H * DOUT, flag, 2);
    hipLaunchKernelGGL(canon_k, dim3(2), dim3(256), 0, stream, b1in, b1c, H, flag, 2);
    hipLaunchKernelGGL(canon_k, dim3(1), dim3(256), 0, stream, bmuin, bmuc, DOUT, flag, 2);
    hipLaunchKernelGGL(canon_k, dim3(1), dim3(256), 0, stream, blsin, blsc, DOUT, flag, 2);

    hipLaunchKernelGGL(deg_init_k, dim3((N + 255) / 256), dim3(256), 0, stream, dinv, N);
    hipLaunchKernelGGL(deg_accum_k, dim3((E + 255) / 256), dim3(256), 0, stream, edges, dinv, E, N);
    hipLaunchKernelGGL(deg_fin_k, dim3((N + 255) / 256), dim3(256), 0, stream, dinv, N);

    // ---- layer 1: t1 = dropout(x) @ W1; h1 = relu(agg(t1))
    hipLaunchKernelGGL(gemm_bf16_k, dim3((N + 63) / 64, H / 64), dim3(256), 0, stream,
                       xcan, W1c, bufB, N, H, DIN, 1);
    long long n1 = (long long)N * H;
    hipLaunchKernelGGL(agg_init_k, dim3((unsigned)((n1 + 255) / 256)), dim3(256), 0, stream,
                       bufB, b1c, dinv, bufA, n1, logH);
    long long s1 = ((long long)E) << logH;
    hipLaunchKernelGGL(agg_scatter_k, dim3((unsigned)((s1 + 255) / 256)), dim3(256), 0, stream,
                       bufB, edges, dinv, bufA, E, N, logH);
    bf16* h1 = xcan;  // reuse: x no longer needed
    hipLaunchKernelGGL(relu_cvt_k, dim3((unsigned)((n1 + 255) / 256)), dim3(256), 0, stream,
                       bufA, h1, n1);

    // ---- layer 2: mu / logstd, aggregated directly into f32 d_out
    hipLaunchKernelGGL(gemm_bf16_k, dim3((N + 63) / 64, DOUT / 64), dim3(256), 0, stream,
                       h1, Wmuc, bufB, N, DOUT, H, 0);
    hipLaunchKernelGGL(gemm_bf16_k, dim3((N + 63) / 64, DOUT / 64), dim3(256), 0, stream,
                       h1, Wlsc, bufB + (size_t)N * DOUT, N, DOUT, H, 0);

    long long n2 = (long long)N * DOUT;
    long long s2 = ((long long)E) << logDOUT;
    hipLaunchKernelGGL(agg_init_k, dim3((unsigned)((n2 + 255) / 256)), dim3(256), 0, stream,
                       bufB, bmuc, dinv, out, n2, logDOUT);
    hipLaunchKernelGGL(agg_scatter_k, dim3((unsigned)((s2 + 255) / 256)), dim3(256), 0, stream,
                       bufB, edges, dinv, out, E, N, logDOUT);
    hipLaunchKernelGGL(agg_init_k, dim3((unsigned)((n2 + 255) / 256)), dim3(256), 0, stream,
                       bufB + (size_t)N * DOUT, blsc, dinv, out + (size_t)N * DOUT, n2, logDOUT);
    hipLaunchKernelGGL(agg_scatter_k, dim3((unsigned)((s2 + 255) / 256)), dim3(256), 0, stream,
                       bufB + (size_t)N * DOUT, edges, dinv, out + (size_t)N * DOUT, E, N, logDOUT);
}

// Round 3
// 1797.912 us; speedup vs baseline: 2.3905x; 2.3905x over previous
//
#include <hip/hip_runtime.h>
#include <hip/hip_bf16.h>

typedef __hip_bfloat16 bf16;

__device__ __forceinline__ float bfu(unsigned short b) {
    unsigned u = ((unsigned)b) << 16;
    float f;
    __builtin_memcpy(&f, &u, 4);
    return f;
}
__device__ __forceinline__ unsigned short f2b(float f) {
    return (unsigned short)(__hip_bfloat16_raw(__float2bfloat16(f)).x);
}

// ---------------------------------------------------------------------------
// Threefry-2x32 (20 rounds), JAX partitionable mode:
//   bits(i) = x0 ^ x1 of threefry2x32(key=(0,42), counter=(hi=0, lo=i))
//   keep    = (bits >> 31) == 0
// ---------------------------------------------------------------------------
__device__ __forceinline__ bool keep_elem(unsigned idx) {
    const unsigned k0 = 0u, k1 = 42u;
    const unsigned k2 = k0 ^ k1 ^ 0x1BD11BDAu;
    unsigned x0 = k0;
    unsigned x1 = idx + k1;
#define TF_QR(R) { x0 += x1; x1 = (x1 << R) | (x1 >> (32 - R)); x1 ^= x0; }
    TF_QR(13) TF_QR(15) TF_QR(26) TF_QR(6)
    x0 += k1; x1 += k2 + 1u;
    TF_QR(17) TF_QR(29) TF_QR(16) TF_QR(24)
    x0 += k2; x1 += k0 + 2u;
    TF_QR(13) TF_QR(15) TF_QR(26) TF_QR(6)
    x0 += k0; x1 += k1 + 3u;
    TF_QR(17) TF_QR(29) TF_QR(16) TF_QR(24)
    x0 += k1; x1 += k2 + 4u;
    TF_QR(13) TF_QR(15) TF_QR(26) TF_QR(6)
    x0 += k2; x1 += k0 + 5u;
#undef TF_QR
    return (((x0 ^ x1) >> 31) & 1u) == 0u;
}

// ---------------------------------------------------------------------------
// Dtype detection (flags): [0] edges int64?, [1] x f32?, [2] weights f32?
// ---------------------------------------------------------------------------
__global__ void detect_edges_k(const unsigned* __restrict__ w, int* __restrict__ flag) {
    __shared__ unsigned red[256];
    unsigned v = 0;
    for (int i = threadIdx.x; i < 2048; i += 256) v |= w[2 * i + 1];
    red[threadIdx.x] = v;
    __syncthreads();
    for (int s = 128; s > 0; s >>= 1) {
        if (threadIdx.x < s) red[threadIdx.x] |= red[threadIdx.x + s];
        __syncthreads();
    }
    if (threadIdx.x == 0) flag[0] = (red[0] == 0u) ? 1 : 0;
}

__global__ void detect_f32_k(const unsigned short* __restrict__ w,
                             int* __restrict__ flag, int fidx) {
    __shared__ int red[256];
    int cnt = 0;
    for (int i = threadIdx.x; i < 1024; i += 256) {
        unsigned short b = w[2 * i];
        int e = (b >> 7) & 0xFF;
        if ((b & 0x7FFF) == 0 || (e >= 100 && e < 140)) cnt++;
    }
    red[threadIdx.x] = cnt;
    __syncthreads();
    for (int s = 128; s > 0; s >>= 1) {
        if (threadIdx.x < s) red[threadIdx.x] += red[threadIdx.x + s];
        __syncthreads();
    }
    if (threadIdx.x == 0) flag[fidx] = (red[0] < 614) ? 1 : 0;
}

__global__ void convert_edges_k(const void* __restrict__ src, int* __restrict__ out,
                                int twoE, const int* __restrict__ flag) {
    int i = blockIdx.x * 256 + threadIdx.x;
    if (i >= twoE) return;
    if (flag[0]) out[i] = (int)((const unsigned long long*)src)[i];
    else         out[i] = ((const int*)src)[i];
}

__global__ void canon_k(const void* __restrict__ src, bf16* __restrict__ dst,
                        int n, const int* __restrict__ flag, int fidx) {
    int i = blockIdx.x * 256 + threadIdx.x;
    if (i >= n) return;
    if (flag[fidx]) dst[i] = __float2bfloat16(((const float*)src)[i]);
    else            dst[i] = ((const bf16*)src)[i];
}

// ---------------------------------------------------------------------------
// CSR build: int degree count -> exclusive scan -> bucket fill
// ---------------------------------------------------------------------------
__global__ void zero_int_k(int* __restrict__ p, int n) {
    int i = blockIdx.x * 256 + threadIdx.x;
    if (i < n) p[i] = 0;
}
__global__ void deg_count_k(const int* __restrict__ edges, int* __restrict__ degi,
                            int E, int n) {
    int e = blockIdx.x * 256 + threadIdx.x;
    if (e >= E) return;
    int d = edges[E + e];
    d = (d < 0) ? 0 : (d >= n ? n - 1 : d);
    atomicAdd(&degi[d], 1);
}
__global__ void dinv_k(const int* __restrict__ degi, float* __restrict__ dinv, int n) {
    int i = blockIdx.x * 256 + threadIdx.x;
    if (i < n) dinv[i] = rsqrtf(1.0f + (float)degi[i]);
}
__global__ void block_sums_k(const int* __restrict__ deg, int* __restrict__ partial, int n) {
    __shared__ int sh[256];
    int i = blockIdx.x * 256 + threadIdx.x;
    sh[threadIdx.x] = (i < n) ? deg[i] : 0;
    __syncthreads();
    for (int s = 128; s > 0; s >>= 1) {
        if (threadIdx.x < s) sh[threadIdx.x] += sh[threadIdx.x + s];
        __syncthreads();
    }
    if (threadIdx.x == 0) partial[blockIdx.x] = sh[0];
}
__global__ void scan_partials_k(int* __restrict__ partial, int G) {  // single block, G<=256
    __shared__ int sh[256];
    int v = (threadIdx.x < G) ? partial[threadIdx.x] : 0;
    sh[threadIdx.x] = v;
    __syncthreads();
    for (int s = 1; s < 256; s <<= 1) {
        int t = 0;
        if (threadIdx.x >= s) t = sh[threadIdx.x - s];
        __syncthreads();
        sh[threadIdx.x] += t;
        __syncthreads();
    }
    if (threadIdx.x < G) partial[threadIdx.x] = sh[threadIdx.x] - v;  // exclusive
}
__global__ void scan_block_k(const int* __restrict__ deg, const int* __restrict__ partial,
                             int* __restrict__ row_ptr, int n) {
    __shared__ int sh[256];
    int i = blockIdx.x * 256 + threadIdx.x;
    int v = (i < n) ? deg[i] : 0;
    sh[threadIdx.x] = v;
    __syncthreads();
    for (int s = 1; s < 256; s <<= 1) {
        int t = 0;
        if (threadIdx.x >= s) t = sh[threadIdx.x - s];
        __syncthreads();
        sh[threadIdx.x] += t;
        __syncthreads();
    }
    int incl = sh[threadIdx.x];
    int base = partial[blockIdx.x];
    if (i < n) row_ptr[i] = base + incl - v;
    if (i == n - 1) row_ptr[n] = base + incl;
}
__global__ void fill_k(const int* __restrict__ edges, const int* __restrict__ row_ptr,
                       int* __restrict__ cnt, int* __restrict__ col, int E, int n) {
    int e = blockIdx.x * 256 + threadIdx.x;
    if (e >= E) return;
    int s = edges[e], d = edges[E + e];
    s = (s < 0) ? 0 : (s >= n ? n - 1 : s);
    d = (d < 0) ? 0 : (d >= n ? n - 1 : d);
    int pos = row_ptr[d] + atomicAdd(&cnt[d], 1);
    col[pos] = s;
}

// ---------------------------------------------------------------------------
// Tiled GEMM: C[M,N] = A[M,K] @ B[K,N]; bf16 in, f32 accumulate.
// Epilogue: if Cf != nullptr -> f32 out with bf16 bias added; else bf16 out.
// fuse_dropout applies threefry mask to A by flat index.
// ---------------------------------------------------------------------------
__global__ __launch_bounds__(256) void gemm_bf16_k(
    const bf16* __restrict__ A, const bf16* __restrict__ B,
    bf16* __restrict__ C, float* __restrict__ Cf, const bf16* __restrict__ bias,
    int M, int Nn, int K, int fuse_dropout) {
    __shared__ float As[32][64];
    __shared__ float Bs[32][64];
    const int t = threadIdx.x;
    const int m0 = blockIdx.x * 64;
    const int n0 = blockIdx.y * 64;
    const int tx = t & 15, ty = t >> 4;
    float acc[4][4] = {};

    for (int kk = 0; kk < K; kk += 32) {
        {
            int q = t * 8;
            int r = q >> 5, c = q & 31;
            int row = m0 + r; if (row >= M) row = M - 1;
            const bf16* ap = A + (size_t)row * K + kk + c;
            unsigned base = (unsigned)row * (unsigned)K + (unsigned)(kk + c);
#pragma unroll
            for (int j = 0; j < 8; ++j) {
                float v = __bfloat162float(ap[j]);
                if (fuse_dropout) v = keep_elem(base + j) ? v * 2.0f : 0.0f;
                As[c + j][r] = v;
            }
        }
        {
            int q = t * 8;
            int r = q >> 6, c = q & 63;
            const bf16* bp = B + (size_t)(kk + r) * Nn + n0 + c;
#pragma unroll
            for (int j = 0; j < 8; ++j) Bs[r][c + j] = __bfloat162float(bp[j]);
        }
        __syncthreads();
#pragma unroll
        for (int k = 0; k < 32; ++k) {
            float a[4], b[4];
#pragma unroll
            for (int i = 0; i < 4; ++i) a[i] = As[k][ty * 4 + i];
#pragma unroll
            for (int j = 0; j < 4; ++j) b[j] = Bs[k][tx * 4 + j];
#pragma unroll
            for (int i = 0; i < 4; ++i)
#pragma unroll
                for (int j = 0; j < 4; ++j) acc[i][j] += a[i] * b[j];
        }
        __syncthreads();
    }
#pragma unroll
    for (int i = 0; i < 4; ++i) {
        int row = m0 + ty * 4 + i;
        if (row >= M) continue;
        if (Cf) {
            float* cp = Cf + (size_t)row * Nn + n0 + tx * 4;
#pragma unroll
            for (int j = 0; j < 4; ++j)
                cp[j] = acc[i][j] + __bfloat162float(bias[n0 + tx * 4 + j]);
        } else {
            bf16* cp = C + (size_t)row * Nn + n0 + tx * 4;
#pragma unroll
            for (int j = 0; j < 4; ++j) cp[j] = __float2bfloat16(acc[i][j]);
        }
    }
}

// ---------------------------------------------------------------------------
// CSR gather: out[node] = sum_{e in row(node)} dinv[src]*dinv[node]*t[src]
//                        + dinv[node]^2 * t[node]  (+bias, relu if mode==1)
// D = 512 features, 256 threads, ushort2 (2 feats) per thread.
// ---------------------------------------------------------------------------
__global__ __launch_bounds__(256) void gather_k(
    const bf16* __restrict__ t, const int* __restrict__ row_ptr,
    const int* __restrict__ col, const float* __restrict__ dinv,
    const bf16* __restrict__ bias, bf16* __restrict__ outp, int mode) {
    const int node = blockIdx.x;
    const int tid = threadIdx.x;
    const ushort2* tp = (const ushort2*)t;
    int beg = row_ptr[node], end = row_ptr[node + 1];
    float dv = dinv[node];
    float a0 = 0.f, a1 = 0.f;
    for (int e = beg; e < end; ++e) {
        int s = col[e];
        float w = dinv[s] * dv;
        ushort2 u = tp[(size_t)s * 256 + tid];
        a0 += w * bfu(u.x);
        a1 += w * bfu(u.y);
    }
    {
        ushort2 u = tp[(size_t)node * 256 + tid];
        float w = dv * dv;
        a0 += w * bfu(u.x);
        a1 += w * bfu(u.y);
    }
    if (mode == 1) {
        a0 += __bfloat162float(bias[2 * tid]);
        a1 += __bfloat162float(bias[2 * tid + 1]);
        a0 = fmaxf(a0, 0.f);
        a1 = fmaxf(a1, 0.f);
    }
    ushort2 o;
    o.x = f2b(a0);
    o.y = f2b(a1);
    ((ushort2*)outp)[(size_t)node * 256 + tid] = o;
}

// ---------------------------------------------------------------------------
extern "C" void kernel_launch(void* const* d_in, const int* in_sizes, int n_in,
                              void* d_out, int out_size, void* d_ws, size_t ws_size,
                              hipStream_t stream) {
    const void* xin   = d_in[0];
    const void* ei    = d_in[1];
    const void* W1in  = d_in[2];
    const void* b1in  = d_in[3];
    const void* Wmuin = d_in[4];
    const void* bmuin = d_in[5];
    const void* Wlsin = d_in[6];
    const void* blsin = d_in[7];
    float* out = (float*)d_out;

    const int H    = in_sizes[3];        // 512
    const int DOUT = in_sizes[5];        // 256
    const int DIN  = in_sizes[2] / H;    // 512
    const int N    = in_sizes[0] / DIN;  // 50000
    const int E    = in_sizes[1] / 2;    // 800000
    const int G    = (N + 255) / 256;    // scan blocks (196 <= 256)

    char* ws = (char*)d_ws;
    size_t off = 0;
    auto alloc = [&](size_t bytes) {
        void* p = ws + off;
        off = (off + bytes + 255) & ~(size_t)255;
        return p;
    };
    int*   flag    = (int*)alloc(256);
    int*   edges   = (int*)alloc((size_t)2 * E * 4);
    int*   degi    = (int*)alloc((size_t)N * 4);
    int*   row_ptr = (int*)alloc((size_t)(N + 1) * 4);
    int*   cnt     = (int*)alloc((size_t)N * 4);
    int*   partial = (int*)alloc((size_t)G * 4);
    int*   col     = (int*)alloc((size_t)E * 4);
    float* dinv    = (float*)alloc((size_t)N * 4);
    bf16*  t1      = (bf16*)alloc((size_t)N * H * 2);
    bf16*  g1      = (bf16*)alloc((size_t)N * H * 2);
    bf16*  xcan    = (bf16*)alloc((size_t)N * DIN * 2);  // reused as h1
    bf16*  W1c     = (bf16*)alloc((size_t)DIN * H * 2);
    bf16*  Wmuc    = (bf16*)alloc((size_t)H * DOUT * 2);
    bf16*  Wlsc    = (bf16*)alloc((size_t)H * DOUT * 2);
    bf16*  b1c     = (bf16*)alloc((size_t)H * 2);
    bf16*  bmuc    = (bf16*)alloc((size_t)DOUT * 2);
    bf16*  blsc    = (bf16*)alloc((size_t)DOUT * 2);
    if (off > ws_size) return;

    const int twoE = 2 * E;
    hipLaunchKernelGGL(detect_edges_k, dim3(1), dim3(256), 0, stream, (const unsigned*)ei, flag);
    hipLaunchKernelGGL(detect_f32_k, dim3(1), dim3(256), 0, stream, (const unsigned short*)xin, flag, 1);
    hipLaunchKernelGGL(detect_f32_k, dim3(1), dim3(256), 0, stream, (const unsigned short*)W1in, flag, 2);

    hipLaunchKernelGGL(convert_edges_k, dim3((twoE + 255) / 256), dim3(256), 0, stream,
                       ei, edges, twoE, flag);
    int nx = N * DIN;
    hipLaunchKernelGGL(canon_k, dim3((nx + 255) / 256), dim3(256), 0, stream, xin, xcan, nx, flag, 1);
    hipLaunchKernelGGL(canon_k, dim3((DIN * H + 255) / 256), dim3(256), 0, stream, W1in, W1c, DIN * H, flag, 2);
    hipLaunchKernelGGL(canon_k, dim3((H * DOUT + 255) / 256), dim3(256), 0, stream, Wmuin, Wmuc, H * DOUT, flag, 2);
    hipLaunchKernelGGL(canon_k, dim3((H * DOUT + 255) / 256), dim3(256), 0, stream, Wlsin, Wlsc, H * DOUT, flag, 2);
    hipLaunchKernelGGL(canon_k, dim3(2), dim3(256), 0, stream, b1in, b1c, H, flag, 2);
    hipLaunchKernelGGL(canon_k, dim3(1), dim3(256), 0, stream, bmuin, bmuc, DOUT, flag, 2);
    hipLaunchKernelGGL(canon_k, dim3(1), dim3(256), 0, stream, blsin, blsc, DOUT, flag, 2);

    // CSR build
    hipLaunchKernelGGL(zero_int_k, dim3(G), dim3(256), 0, stream, degi, N);
    hipLaunchKernelGGL(zero_int_k, dim3(G), dim3(256), 0, stream, cnt, N);
    hipLaunchKernelGGL(deg_count_k, dim3((E + 255) / 256), dim3(256), 0, stream, edges, degi, E, N);
    hipLaunchKernelGGL(dinv_k, dim3(G), dim3(256), 0, stream, degi, dinv, N);
    hipLaunchKernelGGL(block_sums_k, dim3(G), dim3(256), 0, stream, degi, partial, N);
    hipLaunchKernelGGL(scan_partials_k, dim3(1), dim3(256), 0, stream, partial, G);
    hipLaunchKernelGGL(scan_block_k, dim3(G), dim3(256), 0, stream, degi, partial, row_ptr, N);
    hipLaunchKernelGGL(fill_k, dim3((E + 255) / 256), dim3(256), 0, stream, edges, row_ptr, cnt, col, E, N);

    // layer 1: t1 = dropout(x)@W1 ; h1 = relu(gather(t1) + b1)
    hipLaunchKernelGGL(gemm_bf16_k, dim3((N + 63) / 64, H / 64), dim3(256), 0, stream,
                       xcan, W1c, t1, (float*)nullptr, (const bf16*)nullptr, N, H, DIN, 1);
    bf16* h1 = xcan;
    hipLaunchKernelGGL(gather_k, dim3(N), dim3(256), 0, stream,
                       t1, row_ptr, col, dinv, b1c, h1, 1);

    // layer 2: g1 = gather(h1); mu = g1@Wmu + bmu ; logstd = g1@Wls + bls
    hipLaunchKernelGGL(gather_k, dim3(N), dim3(256), 0, stream,
                       h1, row_ptr, col, dinv, (const bf16*)nullptr, g1, 0);
    hipLaunchKernelGGL(gemm_bf16_k, dim3((N + 63) / 64, DOUT / 64), dim3(256), 0, stream,
                       g1, Wmuc, (bf16*)nullptr, out, bmuc, N, DOUT, H, 0);
    hipLaunchKernelGGL(gemm_bf16_k, dim3((N + 63) / 64, DOUT / 64), dim3(256), 0, stream,
                       g1, Wlsc, (bf16*)nullptr, out + (size_t)N * DOUT, blsc, N, DOUT, H, 0);
}

// Round 4
// 822.762 us; speedup vs baseline: 5.2239x; 2.1852x over previous
//
#include <hip/hip_runtime.h>
#include <hip/hip_bf16.h>

typedef __hip_bfloat16 bf16;
typedef __attribute__((ext_vector_type(8))) short short8;
typedef __attribute__((ext_vector_type(4))) float f32x4;

__device__ __forceinline__ float bfu(unsigned short b) {
    unsigned u = ((unsigned)b) << 16;
    float f;
    __builtin_memcpy(&f, &u, 4);
    return f;
}
__device__ __forceinline__ unsigned short f2b(float f) {
    return (unsigned short)(__hip_bfloat16_raw(__float2bfloat16(f)).x);
}

// async global->LDS, 16B per lane; lds dest must be wave-uniform base.
__device__ __forceinline__ void gl_lds16(const void* g, void* l) {
    __builtin_amdgcn_global_load_lds(
        (const __attribute__((address_space(1))) void*)g,
        (__attribute__((address_space(3))) void*)l, 16, 0, 0);
}

// ---------------------------------------------------------------------------
// Threefry-2x32 (20 rounds), JAX partitionable: keep = top bit of (x0^x1)==0
// ---------------------------------------------------------------------------
__device__ __forceinline__ bool keep_elem(unsigned idx) {
    const unsigned k0 = 0u, k1 = 42u;
    const unsigned k2 = k0 ^ k1 ^ 0x1BD11BDAu;
    unsigned x0 = k0;
    unsigned x1 = idx + k1;
#define TF_QR(R) { x0 += x1; x1 = (x1 << R) | (x1 >> (32 - R)); x1 ^= x0; }
    TF_QR(13) TF_QR(15) TF_QR(26) TF_QR(6)
    x0 += k1; x1 += k2 + 1u;
    TF_QR(17) TF_QR(29) TF_QR(16) TF_QR(24)
    x0 += k2; x1 += k0 + 2u;
    TF_QR(13) TF_QR(15) TF_QR(26) TF_QR(6)
    x0 += k0; x1 += k1 + 3u;
    TF_QR(17) TF_QR(29) TF_QR(16) TF_QR(24)
    x0 += k1; x1 += k2 + 4u;
    TF_QR(13) TF_QR(15) TF_QR(26) TF_QR(6)
    x0 += k2; x1 += k0 + 5u;
#undef TF_QR
    return (((x0 ^ x1) >> 31) & 1u) == 0u;
}

// ---------------------------------------------------------------------------
// Dtype detection: flag[0] edges int64?, flag[1] x f32?, flag[2] weights f32?
// ---------------------------------------------------------------------------
__global__ void detect_edges_k(const unsigned* __restrict__ w, int* __restrict__ flag) {
    __shared__ unsigned red[256];
    unsigned v = 0;
    for (int i = threadIdx.x; i < 2048; i += 256) v |= w[2 * i + 1];
    red[threadIdx.x] = v;
    __syncthreads();
    for (int s = 128; s > 0; s >>= 1) {
        if (threadIdx.x < s) red[threadIdx.x] |= red[threadIdx.x + s];
        __syncthreads();
    }
    if (threadIdx.x == 0) flag[0] = (red[0] == 0u) ? 1 : 0;
}

__global__ void detect_f32_k(const unsigned short* __restrict__ w,
                             int* __restrict__ flag, int fidx) {
    __shared__ int red[256];
    int cnt = 0;
    for (int i = threadIdx.x; i < 1024; i += 256) {
        unsigned short b = w[2 * i];
        int e = (b >> 7) & 0xFF;
        if ((b & 0x7FFF) == 0 || (e >= 100 && e < 140)) cnt++;
    }
    red[threadIdx.x] = cnt;
    __syncthreads();
    for (int s = 128; s > 0; s >>= 1) {
        if (threadIdx.x < s) red[threadIdx.x] += red[threadIdx.x + s];
        __syncthreads();
    }
    if (threadIdx.x == 0) flag[fidx] = (red[0] < 614) ? 1 : 0;
}

__global__ void convert_edges_k(const void* __restrict__ src, int* __restrict__ out,
                                int twoE, const int* __restrict__ flag) {
    int i = blockIdx.x * 256 + threadIdx.x;
    if (i >= twoE) return;
    if (flag[0]) out[i] = (int)((const unsigned long long*)src)[i];
    else         out[i] = ((const int*)src)[i];
}

// canonicalize x to bf16 AND apply dropout mask (x2 is exact in bf16)
__global__ void canon_x_drop_k(const void* __restrict__ src, bf16* __restrict__ dst,
                               int n, const int* __restrict__ flag) {
    int i = blockIdx.x * 256 + threadIdx.x;
    if (i >= n) return;
    float v = flag[1] ? ((const float*)src)[i]
                      : __bfloat162float(((const bf16*)src)[i]);
    v = keep_elem((unsigned)i) ? v * 2.0f : 0.0f;
    dst[i] = __float2bfloat16(v);
}

__global__ void canon_k(const void* __restrict__ src, bf16* __restrict__ dst,
                        int n, const int* __restrict__ flag, int fidx) {
    int i = blockIdx.x * 256 + threadIdx.x;
    if (i >= n) return;
    if (flag[fidx]) dst[i] = __float2bfloat16(((const float*)src)[i]);
    else            dst[i] = ((const bf16*)src)[i];
}

// canonicalize + transpose weight [K,Nn] -> [Nn,K] (both multiples of 16)
__global__ void canon_transpose_k(const void* __restrict__ src, unsigned short* __restrict__ dst,
                                  int K, int Nn, const int* __restrict__ flag, int fidx) {
    __shared__ unsigned short tile[16][17];
    int k0 = blockIdx.x * 16, n0 = blockIdx.y * 16;
    int k = k0 + threadIdx.y, n = n0 + threadIdx.x;
    unsigned short v;
    if (flag[fidx]) v = f2b(((const float*)src)[(size_t)k * Nn + n]);
    else            v = ((const unsigned short*)src)[(size_t)k * Nn + n];
    tile[threadIdx.y][threadIdx.x] = v;
    __syncthreads();
    int nn = n0 + threadIdx.y, kk = k0 + threadIdx.x;
    dst[(size_t)nn * K + kk] = tile[threadIdx.x][threadIdx.y];
}

// ---------------------------------------------------------------------------
// CSR build
// ---------------------------------------------------------------------------
__global__ void zero_int_k(int* __restrict__ p, int n) {
    int i = blockIdx.x * 256 + threadIdx.x;
    if (i < n) p[i] = 0;
}
__global__ void deg_count_k(const int* __restrict__ edges, int* __restrict__ degi,
                            int E, int n) {
    int e = blockIdx.x * 256 + threadIdx.x;
    if (e >= E) return;
    int d = edges[E + e];
    d = (d < 0) ? 0 : (d >= n ? n - 1 : d);
    atomicAdd(&degi[d], 1);
}
__global__ void dinv_k(const int* __restrict__ degi, float* __restrict__ dinv, int n) {
    int i = blockIdx.x * 256 + threadIdx.x;
    if (i < n) dinv[i] = rsqrtf(1.0f + (float)degi[i]);
}
__global__ void block_sums_k(const int* __restrict__ deg, int* __restrict__ partial, int n) {
    __shared__ int sh[256];
    int i = blockIdx.x * 256 + threadIdx.x;
    sh[threadIdx.x] = (i < n) ? deg[i] : 0;
    __syncthreads();
    for (int s = 128; s > 0; s >>= 1) {
        if (threadIdx.x < s) sh[threadIdx.x] += sh[threadIdx.x + s];
        __syncthreads();
    }
    if (threadIdx.x == 0) partial[blockIdx.x] = sh[0];
}
__global__ void scan_partials_k(int* __restrict__ partial, int G) {
    __shared__ int sh[256];
    int v = (threadIdx.x < G) ? partial[threadIdx.x] : 0;
    sh[threadIdx.x] = v;
    __syncthreads();
    for (int s = 1; s < 256; s <<= 1) {
        int t = 0;
        if (threadIdx.x >= s) t = sh[threadIdx.x - s];
        __syncthreads();
        sh[threadIdx.x] += t;
        __syncthreads();
    }
    if (threadIdx.x < G) partial[threadIdx.x] = sh[threadIdx.x] - v;
}
__global__ void scan_block_k(const int* __restrict__ deg, const int* __restrict__ partial,
                             int* __restrict__ row_ptr, int n) {
    __shared__ int sh[256];
    int i = blockIdx.x * 256 + threadIdx.x;
    int v = (i < n) ? deg[i] : 0;
    sh[threadIdx.x] = v;
    __syncthreads();
    for (int s = 1; s < 256; s <<= 1) {
        int t = 0;
        if (threadIdx.x >= s) t = sh[threadIdx.x - s];
        __syncthreads();
        sh[threadIdx.x] += t;
        __syncthreads();
    }
    int incl = sh[threadIdx.x];
    int base = partial[blockIdx.x];
    if (i < n) row_ptr[i] = base + incl - v;
    if (i == n - 1) row_ptr[n] = base + incl;
}
__global__ void fill_k(const int* __restrict__ edges, const int* __restrict__ row_ptr,
                       int* __restrict__ cnt, int* __restrict__ col, int E, int n) {
    int e = blockIdx.x * 256 + threadIdx.x;
    if (e >= E) return;
    int s = edges[e], d = edges[E + e];
    s = (s < 0) ? 0 : (s >= n ? n - 1 : s);
    d = (d < 0) ? 0 : (d >= n ? n - 1 : d);
    int pos = row_ptr[d] + atomicAdd(&cnt[d], 1);
    col[pos] = s;
}

// ---------------------------------------------------------------------------
// MFMA GEMM (m97 structure): C[M,Nn] = A[M,K] @ Bt[Nn,K]^T
// 128x128 tile, BK=32, 4 waves in 2x2, each wave 4x4 of 16x16x32 bf16 MFMA.
// Epilogue: Cf!=null -> f32 out + bf16 bias; else bf16 out.
// ---------------------------------------------------------------------------
__global__ __launch_bounds__(256) void gemm_mfma_k(
    const bf16* __restrict__ A, const bf16* __restrict__ Bt,
    bf16* __restrict__ Cb, float* __restrict__ Cf, const bf16* __restrict__ bias,
    int M, int Nn, int K) {
    __shared__ short sA[128 * 32];
    __shared__ short sB[128 * 32];
    const int tid = threadIdx.x;
    const int lane = tid & 63;
    const int w = tid >> 6;
    const int m0 = blockIdx.x * 128;
    const int n0 = blockIdx.y * 128;
    const int wm = (w >> 1) * 64;
    const int wn = (w & 1) * 64;

    f32x4 acc[4][4] = {};

    const int srow = lane >> 2;        // 0..15 within a 16-row group
    const int scol = (lane & 3) * 8;   // k offset 0/8/16/24

    for (int kk = 0; kk < K; kk += 32) {
#pragma unroll
        for (int q = 0; q < 2; ++q) {  // A tile: rows q*64 + w*16 + srow
            int r = q * 64 + w * 16 + srow;
            int grow = m0 + r; if (grow >= M) grow = M - 1;
            gl_lds16(A + (size_t)grow * K + kk + scol, &sA[q * 2048 + w * 512 + lane * 8]);
        }
#pragma unroll
        for (int q = 0; q < 2; ++q) {  // B tile (Nn multiple of 128, no clamp)
            int r = q * 64 + w * 16 + srow;
            gl_lds16(Bt + (size_t)(n0 + r) * K + kk + scol, &sB[q * 2048 + w * 512 + lane * 8]);
        }
        __syncthreads();

        const int fr = lane & 15;
        const int fk = (lane >> 4) * 8;
        short8 af[4], bfr[4];
#pragma unroll
        for (int i = 0; i < 4; ++i)
            af[i] = *(const short8*)&sA[(wm + i * 16 + fr) * 32 + fk];
#pragma unroll
        for (int j = 0; j < 4; ++j)
            bfr[j] = *(const short8*)&sB[(wn + j * 16 + fr) * 32 + fk];
#pragma unroll
        for (int i = 0; i < 4; ++i)
#pragma unroll
            for (int j = 0; j < 4; ++j)
                acc[i][j] = __builtin_amdgcn_mfma_f32_16x16x32_bf16(
                    af[i], bfr[j], acc[i][j], 0, 0, 0);
        __syncthreads();
    }

    const int crow = (lane >> 4) * 4;
    const int ccol = lane & 15;
#pragma unroll
    for (int i = 0; i < 4; ++i) {
#pragma unroll
        for (int r = 0; r < 4; ++r) {
            int row = m0 + wm + i * 16 + crow + r;
            if (row >= M) continue;
            if (Cf) {
                float* cp = Cf + (size_t)row * Nn + n0 + wn;
#pragma unroll
                for (int j = 0; j < 4; ++j) {
                    int c = j * 16 + ccol;
                    cp[c] = acc[i][j][r] + __bfloat162float(bias[n0 + wn + c]);
                }
            } else {
                bf16* cp = Cb + (size_t)row * Nn + n0 + wn;
#pragma unroll
                for (int j = 0; j < 4; ++j)
                    cp[j * 16 + ccol] = __float2bfloat16(acc[i][j][r]);
            }
        }
    }
}

// ---------------------------------------------------------------------------
// CSR gather: out[node] = sum_edges dinv[s]*dinv[node]*t[s] + dinv[node]^2*t[node]
// (+bias, relu if mode==1). 512 feats, 256 threads, ushort2/thread.
// ---------------------------------------------------------------------------
__global__ __launch_bounds__(256) void gather_k(
    const bf16* __restrict__ t, const int* __restrict__ row_ptr,
    const int* __restrict__ col, const float* __restrict__ dinv,
    const bf16* __restrict__ bias, bf16* __restrict__ outp, int mode) {
    const int node = blockIdx.x;
    const int tid = threadIdx.x;
    const ushort2* tp = (const ushort2*)t;
    int beg = row_ptr[node], end = row_ptr[node + 1];
    float dv = dinv[node];
    float a0 = 0.f, a1 = 0.f;
    for (int e = beg; e < end; ++e) {
        int s = col[e];
        float w = dinv[s] * dv;
        ushort2 u = tp[(size_t)s * 256 + tid];
        a0 += w * bfu(u.x);
        a1 += w * bfu(u.y);
    }
    {
        ushort2 u = tp[(size_t)node * 256 + tid];
        float w = dv * dv;
        a0 += w * bfu(u.x);
        a1 += w * bfu(u.y);
    }
    if (mode == 1) {
        a0 += __bfloat162float(bias[2 * tid]);
        a1 += __bfloat162float(bias[2 * tid + 1]);
        a0 = fmaxf(a0, 0.f);
        a1 = fmaxf(a1, 0.f);
    }
    ushort2 o;
    o.x = f2b(a0);
    o.y = f2b(a1);
    ((ushort2*)outp)[(size_t)node * 256 + tid] = o;
}

// ---------------------------------------------------------------------------
extern "C" void kernel_launch(void* const* d_in, const int* in_sizes, int n_in,
                              void* d_out, int out_size, void* d_ws, size_t ws_size,
                              hipStream_t stream) {
    const void* xin   = d_in[0];
    const void* ei    = d_in[1];
    const void* W1in  = d_in[2];
    const void* b1in  = d_in[3];
    const void* Wmuin = d_in[4];
    const void* bmuin = d_in[5];
    const void* Wlsin = d_in[6];
    const void* blsin = d_in[7];
    float* out = (float*)d_out;

    const int H    = in_sizes[3];        // 512
    const int DOUT = in_sizes[5];        // 256
    const int DIN  = in_sizes[2] / H;    // 512
    const int N    = in_sizes[0] / DIN;  // 50000
    const int E    = in_sizes[1] / 2;    // 800000
    const int G    = (N + 255) / 256;

    char* ws = (char*)d_ws;
    size_t off = 0;
    auto alloc = [&](size_t bytes) {
        void* p = ws + off;
        off = (off + bytes + 255) & ~(size_t)255;
        return p;
    };
    int*   flag    = (int*)alloc(256);
    int*   edges   = (int*)alloc((size_t)2 * E * 4);
    int*   degi    = (int*)alloc((size_t)N * 4);
    int*   row_ptr = (int*)alloc((size_t)(N + 1) * 4);
    int*   cnt     = (int*)alloc((size_t)N * 4);
    int*   partial = (int*)alloc((size_t)G * 4);
    int*   col     = (int*)alloc((size_t)E * 4);
    float* dinv    = (float*)alloc((size_t)N * 4);
    bf16*  t1      = (bf16*)alloc((size_t)N * H * 2);
    bf16*  g1      = (bf16*)alloc((size_t)N * H * 2);
    bf16*  xdrop   = (bf16*)alloc((size_t)N * DIN * 2);  // reused as h1
    bf16*  W1t     = (bf16*)alloc((size_t)DIN * H * 2);  // [H, DIN]
    bf16*  Wmut    = (bf16*)alloc((size_t)H * DOUT * 2); // [DOUT, H]
    bf16*  Wlst    = (bf16*)alloc((size_t)H * DOUT * 2);
    bf16*  b1c     = (bf16*)alloc((size_t)H * 2);
    bf16*  bmuc    = (bf16*)alloc((size_t)DOUT * 2);
    bf16*  blsc    = (bf16*)alloc((size_t)DOUT * 2);
    if (off > ws_size) return;

    const int twoE = 2 * E;
    hipLaunchKernelGGL(detect_edges_k, dim3(1), dim3(256), 0, stream, (const unsigned*)ei, flag);
    hipLaunchKernelGGL(detect_f32_k, dim3(1), dim3(256), 0, stream, (const unsigned short*)xin, flag, 1);
    hipLaunchKernelGGL(detect_f32_k, dim3(1), dim3(256), 0, stream, (const unsigned short*)W1in, flag, 2);

    hipLaunchKernelGGL(convert_edges_k, dim3((twoE + 255) / 256), dim3(256), 0, stream,
                       ei, edges, twoE, flag);
    int nx = N * DIN;
    hipLaunchKernelGGL(canon_x_drop_k, dim3((nx + 255) / 256), dim3(256), 0, stream,
                       xin, xdrop, nx, flag);
    hipLaunchKernelGGL(canon_transpose_k, dim3(DIN / 16, H / 16), dim3(16, 16), 0, stream,
                       W1in, (unsigned short*)W1t, DIN, H, flag, 2);
    hipLaunchKernelGGL(canon_transpose_k, dim3(H / 16, DOUT / 16), dim3(16, 16), 0, stream,
                       Wmuin, (unsigned short*)Wmut, H, DOUT, flag, 2);
    hipLaunchKernelGGL(canon_transpose_k, dim3(H / 16, DOUT / 16), dim3(16, 16), 0, stream,
                       Wlsin, (unsigned short*)Wlst, H, DOUT, flag, 2);
    hipLaunchKernelGGL(canon_k, dim3(2), dim3(256), 0, stream, b1in, b1c, H, flag, 2);
    hipLaunchKernelGGL(canon_k, dim3(1), dim3(256), 0, stream, bmuin, bmuc, DOUT, flag, 2);
    hipLaunchKernelGGL(canon_k, dim3(1), dim3(256), 0, stream, blsin, blsc, DOUT, flag, 2);

    // CSR build
    hipLaunchKernelGGL(zero_int_k, dim3(G), dim3(256), 0, stream, degi, N);
    hipLaunchKernelGGL(zero_int_k, dim3(G), dim3(256), 0, stream, cnt, N);
    hipLaunchKernelGGL(deg_count_k, dim3((E + 255) / 256), dim3(256), 0, stream, edges, degi, E, N);
    hipLaunchKernelGGL(dinv_k, dim3(G), dim3(256), 0, stream, degi, dinv, N);
    hipLaunchKernelGGL(block_sums_k, dim3(G), dim3(256), 0, stream, degi, partial, N);
    hipLaunchKernelGGL(scan_partials_k, dim3(1), dim3(256), 0, stream, partial, G);
    hipLaunchKernelGGL(scan_block_k, dim3(G), dim3(256), 0, stream, degi, partial, row_ptr, N);
    hipLaunchKernelGGL(fill_k, dim3((E + 255) / 256), dim3(256), 0, stream, edges, row_ptr, cnt, col, E, N);

    // layer 1: t1 = xdrop @ W1 ; h1 = relu(gather(t1) + b1)
    hipLaunchKernelGGL(gemm_mfma_k, dim3((N + 127) / 128, H / 128), dim3(256), 0, stream,
                       xdrop, W1t, t1, (float*)nullptr, (const bf16*)nullptr, N, H, DIN);
    bf16* h1 = xdrop;
    hipLaunchKernelGGL(gather_k, dim3(N), dim3(256), 0, stream,
                       t1, row_ptr, col, dinv, b1c, h1, 1);

    // layer 2: g1 = gather(h1); mu = g1@Wmu + bmu ; logstd = g1@Wls + bls
    hipLaunchKernelGGL(gather_k, dim3(N), dim3(256), 0, stream,
                       h1, row_ptr, col, dinv, (const bf16*)nullptr, g1, 0);
    hipLaunchKernelGGL(gemm_mfma_k, dim3((N + 127) / 128, DOUT / 128), dim3(256), 0, stream,
                       g1, Wmut, (bf16*)nullptr, out, bmuc, N, DOUT, H);
    hipLaunchKernelGGL(gemm_mfma_k, dim3((N + 127) / 128, DOUT / 128), dim3(256), 0, stream,
                       g1, Wlst, (bf16*)nullptr, out + (size_t)N * DOUT, blsc, N, DOUT, H);
}